// Round 3
// baseline (580.754 us; speedup 1.0000x reference)
//
#include <hip/hip_runtime.h>

#define DF 128
constexpr int N_NODES = 10000;
constexpr int N_EDGES = 640000;

typedef __bf16 bf16x8 __attribute__((ext_vector_type(8)));
typedef float f32x4 __attribute__((ext_vector_type(4)));

// ---------- helpers ----------
__device__ __forceinline__ unsigned short f2bf(float f) {
  unsigned u = __builtin_bit_cast(unsigned, f);
  u += 0x7fffu + ((u >> 16) & 1u);   // RTNE
  return (unsigned short)(u >> 16);
}

__device__ __forceinline__ bf16x8 cvt8(float4 a, float4 b) {
  bf16x8 r;
  r[0] = (__bf16)a.x; r[1] = (__bf16)a.y; r[2] = (__bf16)a.z; r[3] = (__bf16)a.w;
  r[4] = (__bf16)b.x; r[5] = (__bf16)b.y; r[6] = (__bf16)b.z; r[7] = (__bf16)b.w;
  return r;
}

// stage a 16x128 C-layout tile (relu'd) into a 4KB LDS buffer, XOR-swizzled
// (HW-verified in round 1)
__device__ __forceinline__ void stage_h(char* bufj, const f32x4* accv, int grp, int row16) {
#pragma unroll
  for (int nt = 0; nt < 8; ++nt)
#pragma unroll
    for (int i = 0; i < 4; ++i) {
      const int r = grp * 4 + i;
      const int c = nt * 16 + row16;
      *(unsigned short*)(bufj + ((r * 256 + c * 2) ^ ((r & 7) << 4))) =
          f2bf(fmaxf(accv[nt][i], 0.f));
    }
}

// read an A-fragment (16 rows x 32 k) from a swizzled 4KB buffer (HW-verified)
__device__ __forceinline__ bf16x8 read_a(const char* bufj, int kt, int grp, int row16) {
  return *(const bf16x8*)(bufj + ((row16 * 256 + kt * 64 + grp * 16) ^ ((row16 & 7) << 4)));
}

// ---------- kernel 1: pack all weights to bf16 K32 B-frag order (round-1 layout,
// HW-verified) + convert node table to bf16 ----------
__global__ void pack_prep(const float* __restrict__ w0, const float* __restrict__ w1,
                          const float* __restrict__ w2, const float* __restrict__ nw0,
                          const float* __restrict__ nw1, const float* __restrict__ nw2,
                          const float* __restrict__ wn, const float* __restrict__ nodes,
                          unsigned short* __restrict__ dst, unsigned short* __restrict__ nbf) {
  int tid = blockIdx.x * blockDim.x + threadIdx.x;
  if (tid >= 163840 + N_NODES * DF) return;
  if (tid >= 163840) {                       // nodes -> bf16
    int p = tid - 163840;
    nbf[p] = f2bf(nodes[p]);
    return;
  }
  const float* src; int p;
  if (tid < 49152)       { src = w0;  p = tid; }
  else if (tid < 65536)  { src = w1;  p = tid - 49152; }
  else if (tid < 81920)  { src = w2;  p = tid - 65536; }
  else if (tid < 114688) { src = nw0; p = tid - 81920; }
  else if (tid < 131072) { src = nw1; p = tid - 114688; }
  else if (tid < 147456) { src = nw2; p = tid - 131072; }
  else                   { src = wn;  p = tid - 147456; }
  int i = p & 7, lane = (p >> 3) & 63, tile = p >> 9;
  int nt = tile & 7, kt = tile >> 3;
  int k = kt * 32 + ((lane >> 4) << 3) + i;
  int n = nt * 16 + (lane & 15);
  dst[tid] = f2bf(src[k * 128 + n]);
}

// ---------- kernel 2: fused message MLP + scatter-add ----------
// 256 thr = 4 waves, 32 edges/wave (2 subtiles of 16), 128 edges/block, grid 5000.
// Round-1 math exactly; weights streamed from L2 (no LDS weight staging);
// per-wave 8KB LDS for the two inter-layer transposes.
__global__ void __launch_bounds__(256, 4) msg_kernel(
    const float* __restrict__ edges,
    const int* __restrict__ senders, const int* __restrict__ receivers,
    const float* __restrict__ b0, const float* __restrict__ b1, const float* __restrict__ b2,
    const unsigned short* __restrict__ pw, const unsigned short* __restrict__ nbf,
    float* __restrict__ agg) {
  __shared__ char hs[32768];
  const int tid = threadIdx.x;
  const int lane = tid & 63, wave = tid >> 6;
  const int row16 = lane & 15, grp = lane >> 4;
  char* hb = hs + wave * 8192;
  const int rbase = blockIdx.x * 128 + wave * 32;

  const int e0 = rbase + row16, e1 = rbase + 16 + row16;
  const int sx0 = senders[e0], sx1 = senders[e1];
  const int rx0 = receivers[e0], rx1 = receivers[e1];

  // ---- layer 0: K = 384 = [sender | receiver | edge], standard orientation ----
  f32x4 acc[2][8];
#pragma unroll
  for (int nt = 0; nt < 8; ++nt) {
    float bv = b0[nt * 16 + row16];
    acc[0][nt] = (f32x4){bv, bv, bv, bv};
    acc[1][nt] = (f32x4){bv, bv, bv, bv};
  }
#pragma unroll
  for (int ktg = 0; ktg < 12; ++ktg) {
    const int kc = ktg >> 2, k2 = ktg & 3;
    bf16x8 af0, af1;
    if (kc == 0) {
      af0 = *(const bf16x8*)(nbf + (size_t)sx0 * DF + k2 * 32 + grp * 8);
      af1 = *(const bf16x8*)(nbf + (size_t)sx1 * DF + k2 * 32 + grp * 8);
    } else if (kc == 1) {
      af0 = *(const bf16x8*)(nbf + (size_t)rx0 * DF + k2 * 32 + grp * 8);
      af1 = *(const bf16x8*)(nbf + (size_t)rx1 * DF + k2 * 32 + grp * 8);
    } else {
      const float* p0 = edges + (size_t)e0 * DF + k2 * 32 + grp * 8;
      const float* p1 = edges + (size_t)e1 * DF + k2 * 32 + grp * 8;
      af0 = cvt8(*(const float4*)p0, *(const float4*)(p0 + 4));
      af1 = cvt8(*(const float4*)p1, *(const float4*)(p1 + 4));
    }
#pragma unroll
    for (int nt = 0; nt < 8; ++nt) {
      bf16x8 bw = *(const bf16x8*)(pw + ((size_t)(ktg * 8 + nt) * 64 + lane) * 8);
      acc[0][nt] = __builtin_amdgcn_mfma_f32_16x16x32_bf16(af0, bw, acc[0][nt], 0, 0, 0);
      acc[1][nt] = __builtin_amdgcn_mfma_f32_16x16x32_bf16(af1, bw, acc[1][nt], 0, 0, 0);
    }
  }

  // transpose h1 through per-wave LDS (round-1 verified path)
  stage_h(hb, acc[0], grp, row16);
  stage_h(hb + 4096, acc[1], grp, row16);
  asm volatile("s_waitcnt lgkmcnt(0)" ::: "memory");
  __builtin_amdgcn_sched_barrier(0);

  // ---- layer 1 ----
  f32x4 acc2[2][8];
#pragma unroll
  for (int nt = 0; nt < 8; ++nt) {
    float bv = b1[nt * 16 + row16];
    acc2[0][nt] = (f32x4){bv, bv, bv, bv};
    acc2[1][nt] = (f32x4){bv, bv, bv, bv};
  }
  const unsigned short* w1p = pw + 49152;
#pragma unroll
  for (int kt = 0; kt < 4; ++kt) {
    bf16x8 af0 = read_a(hb, kt, grp, row16);
    bf16x8 af1 = read_a(hb + 4096, kt, grp, row16);
#pragma unroll
    for (int nt = 0; nt < 8; ++nt) {
      bf16x8 bw = *(const bf16x8*)(w1p + ((size_t)(kt * 8 + nt) * 64 + lane) * 8);
      acc2[0][nt] = __builtin_amdgcn_mfma_f32_16x16x32_bf16(af0, bw, acc2[0][nt], 0, 0, 0);
      acc2[1][nt] = __builtin_amdgcn_mfma_f32_16x16x32_bf16(af1, bw, acc2[1][nt], 0, 0, 0);
    }
  }
  asm volatile("s_waitcnt lgkmcnt(0)" ::: "memory");  // reads done before overwrite
  __builtin_amdgcn_sched_barrier(0);

  stage_h(hb, acc2[0], grp, row16);
  stage_h(hb + 4096, acc2[1], grp, row16);
  asm volatile("s_waitcnt lgkmcnt(0)" ::: "memory");
  __builtin_amdgcn_sched_barrier(0);

  // ---- layer 2 (no relu) ----
  f32x4 acc3[2][8];
#pragma unroll
  for (int nt = 0; nt < 8; ++nt) {
    float bv = b2[nt * 16 + row16];
    acc3[0][nt] = (f32x4){bv, bv, bv, bv};
    acc3[1][nt] = (f32x4){bv, bv, bv, bv};
  }
  const unsigned short* w2p = pw + 65536;
#pragma unroll
  for (int kt = 0; kt < 4; ++kt) {
    bf16x8 af0 = read_a(hb, kt, grp, row16);
    bf16x8 af1 = read_a(hb + 4096, kt, grp, row16);
#pragma unroll
    for (int nt = 0; nt < 8; ++nt) {
      bf16x8 bw = *(const bf16x8*)(w2p + ((size_t)(kt * 8 + nt) * 64 + lane) * 8);
      acc3[0][nt] = __builtin_amdgcn_mfma_f32_16x16x32_bf16(af0, bw, acc3[0][nt], 0, 0, 0);
      acc3[1][nt] = __builtin_amdgcn_mfma_f32_16x16x32_bf16(af1, bw, acc3[1][nt], 0, 0, 0);
    }
  }

  // ---- scatter (round-1 verified indexing) ----
#pragma unroll
  for (int j = 0; j < 2; ++j) {
    int rr[4];
#pragma unroll
    for (int i = 0; i < 4; ++i) rr[i] = receivers[rbase + j * 16 + grp * 4 + i];
#pragma unroll
    for (int nt = 0; nt < 8; ++nt)
#pragma unroll
      for (int i = 0; i < 4; ++i)
        unsafeAtomicAdd(agg + (size_t)rr[i] * DF + nt * 16 + row16, acc3[j][nt][i]);
  }
}

// ---------- kernel 3: node MLP + residual + LayerNorm (round-1 verified, unchanged) ----------
__global__ void __launch_bounds__(256) node_kernel(
    const float* __restrict__ nodes, const float* __restrict__ agg,
    const float* __restrict__ nb0, const float* __restrict__ nb1, const float* __restrict__ nb2,
    const unsigned short* __restrict__ pnw0, const unsigned short* __restrict__ pnw1,
    const unsigned short* __restrict__ pnw2, const unsigned short* __restrict__ pwn,
    const float* __restrict__ ln_s, const float* __restrict__ ln_b,
    float* __restrict__ out) {
  __shared__ char hs[16384];
  const int tid = threadIdx.x, lane = tid & 63, wave = tid >> 6;
  const int row16 = lane & 15, grp = lane >> 4;
  char* hb = hs + wave * 4096;
  const int rb = blockIdx.x * 64 + wave * 16;
  const int rA = min(rb + row16, N_NODES - 1);

  f32x4 acc[8];
#pragma unroll
  for (int nt = 0; nt < 8; ++nt) {
    float b = nb0[nt * 16 + row16];
    acc[nt] = (f32x4){b, b, b, b};
  }
#pragma unroll
  for (int kt = 0; kt < 8; ++kt) {
    const float* p = (kt < 4) ? (nodes + (size_t)rA * DF + kt * 32)
                              : (agg + (size_t)rA * DF + (kt - 4) * 32);
    p += grp * 8;
    float4 f0 = *(const float4*)p, f1 = *(const float4*)(p + 4);
    bf16x8 af = cvt8(f0, f1);
#pragma unroll
    for (int nt = 0; nt < 8; ++nt) {
      bf16x8 bw = *(const bf16x8*)(pnw0 + ((size_t)(kt * 8 + nt) * 64 + lane) * 8);
      acc[nt] = __builtin_amdgcn_mfma_f32_16x16x32_bf16(af, bw, acc[nt], 0, 0, 0);
    }
  }
  stage_h(hb, acc, grp, row16);
  asm volatile("s_waitcnt lgkmcnt(0)" ::: "memory");
  __builtin_amdgcn_sched_barrier(0);

  f32x4 acc2[8];
#pragma unroll
  for (int nt = 0; nt < 8; ++nt) {
    float b = nb1[nt * 16 + row16];
    acc2[nt] = (f32x4){b, b, b, b};
  }
#pragma unroll
  for (int kt = 0; kt < 4; ++kt) {
    bf16x8 af = read_a(hb, kt, grp, row16);
#pragma unroll
    for (int nt = 0; nt < 8; ++nt) {
      bf16x8 bw = *(const bf16x8*)(pnw1 + ((size_t)(kt * 8 + nt) * 64 + lane) * 8);
      acc2[nt] = __builtin_amdgcn_mfma_f32_16x16x32_bf16(af, bw, acc2[nt], 0, 0, 0);
    }
  }
  asm volatile("s_waitcnt lgkmcnt(0)" ::: "memory");
  __builtin_amdgcn_sched_barrier(0);
  stage_h(hb, acc2, grp, row16);
  asm volatile("s_waitcnt lgkmcnt(0)" ::: "memory");
  __builtin_amdgcn_sched_barrier(0);

  f32x4 acc3[8];
#pragma unroll
  for (int nt = 0; nt < 8; ++nt) {
    float b = nb2[nt * 16 + row16];
    acc3[nt] = (f32x4){b, b, b, b};
  }
#pragma unroll
  for (int kt = 0; kt < 4; ++kt) {
    bf16x8 af = read_a(hb, kt, grp, row16);
#pragma unroll
    for (int nt = 0; nt < 8; ++nt) {
      bf16x8 bw = *(const bf16x8*)(pnw2 + ((size_t)(kt * 8 + nt) * 64 + lane) * 8);
      acc3[nt] = __builtin_amdgcn_mfma_f32_16x16x32_bf16(af, bw, acc3[nt], 0, 0, 0);
    }
  }
  f32x4 accR[8];
#pragma unroll
  for (int nt = 0; nt < 8; ++nt) accR[nt] = (f32x4){0.f, 0.f, 0.f, 0.f};
#pragma unroll
  for (int kt = 0; kt < 4; ++kt) {
    const float* p = nodes + (size_t)rA * DF + kt * 32 + grp * 8;
    float4 f0 = *(const float4*)p, f1 = *(const float4*)(p + 4);
    bf16x8 af = cvt8(f0, f1);
#pragma unroll
    for (int nt = 0; nt < 8; ++nt) {
      bf16x8 bw = *(const bf16x8*)(pwn + ((size_t)(kt * 8 + nt) * 64 + lane) * 8);
      accR[nt] = __builtin_amdgcn_mfma_f32_16x16x32_bf16(af, bw, accR[nt], 0, 0, 0);
    }
  }

  float y[8][4];
#pragma unroll
  for (int nt = 0; nt < 8; ++nt)
#pragma unroll
    for (int i = 0; i < 4; ++i) y[nt][i] = acc3[nt][i] + accR[nt][i];

  float mean[4], rstd[4];
#pragma unroll
  for (int i = 0; i < 4; ++i) {
    float s = 0.f;
#pragma unroll
    for (int nt = 0; nt < 8; ++nt) s += y[nt][i];
    s += __shfl_xor(s, 1); s += __shfl_xor(s, 2);
    s += __shfl_xor(s, 4); s += __shfl_xor(s, 8);
    mean[i] = s * (1.0f / 128.0f);
  }
#pragma unroll
  for (int i = 0; i < 4; ++i) {
    float v = 0.f;
#pragma unroll
    for (int nt = 0; nt < 8; ++nt) {
      float d = y[nt][i] - mean[i];
      v += d * d;
    }
    v += __shfl_xor(v, 1); v += __shfl_xor(v, 2);
    v += __shfl_xor(v, 4); v += __shfl_xor(v, 8);
    rstd[i] = rsqrtf(v * (1.0f / 128.0f) + 1e-6f);
  }
#pragma unroll
  for (int nt = 0; nt < 8; ++nt) {
    const float ls = ln_s[nt * 16 + row16];
    const float lb = ln_b[nt * 16 + row16];
#pragma unroll
    for (int i = 0; i < 4; ++i) {
      const int r = rb + grp * 4 + i;
      if (r < N_NODES)
        out[(size_t)r * DF + nt * 16 + row16] = (y[nt][i] - mean[i]) * rstd[i] * ls + lb;
    }
  }
}

// ---------- launch ----------
extern "C" void kernel_launch(void* const* d_in, const int* in_sizes, int n_in,
                              void* d_out, int out_size, void* d_ws, size_t ws_size,
                              hipStream_t stream) {
  const float* nodes     = (const float*)d_in[0];
  const float* edges     = (const float*)d_in[1];
  const int*   senders   = (const int*)d_in[2];
  const int*   receivers = (const int*)d_in[3];
  const float* msg_w0 = (const float*)d_in[4];
  const float* msg_b0 = (const float*)d_in[5];
  const float* msg_w1 = (const float*)d_in[6];
  const float* msg_b1 = (const float*)d_in[7];
  const float* msg_w2 = (const float*)d_in[8];
  const float* msg_b2 = (const float*)d_in[9];
  const float* node_w0 = (const float*)d_in[10];
  const float* node_b0 = (const float*)d_in[11];
  const float* node_w1 = (const float*)d_in[12];
  const float* node_b1 = (const float*)d_in[13];
  const float* node_w2 = (const float*)d_in[14];
  const float* node_b2 = (const float*)d_in[15];
  const float* w_node   = (const float*)d_in[16];
  const float* ln_scale = (const float*)d_in[17];
  const float* ln_bias  = (const float*)d_in[18];

  float* agg = (float*)d_ws;                                         // 5,120,000 B
  unsigned short* pw  = (unsigned short*)((char*)d_ws + 5120000);    // 327,680 B
  unsigned short* nbf = (unsigned short*)((char*)d_ws + 5447680);    // 2,560,000 B

  hipMemsetAsync(agg, 0, (size_t)N_NODES * DF * sizeof(float), stream);
  pack_prep<<<(163840 + N_NODES * DF) / 256, 256, 0, stream>>>(
      msg_w0, msg_w1, msg_w2, node_w0, node_w1, node_w2, w_node, nodes, pw, nbf);

  msg_kernel<<<N_EDGES / 128, 256, 0, stream>>>(
      edges, senders, receivers, msg_b0, msg_b1, msg_b2, pw, nbf, agg);

  node_kernel<<<157, 256, 0, stream>>>(nodes, agg, node_b0, node_b1, node_b2,
                                       pw + 81920, pw + 114688, pw + 131072, pw + 147456,
                                       ln_scale, ln_bias, (float*)d_out);
}

// Round 4
// 538.596 us; speedup vs baseline: 1.0783x; 1.0783x over previous
//
#include <hip/hip_runtime.h>

#define DF 128
constexpr int N_NODES = 10000;
constexpr int N_EDGES = 640000;

typedef __bf16 bf16x8 __attribute__((ext_vector_type(8)));
typedef float f32x4 __attribute__((ext_vector_type(4)));

// ---------- helpers ----------
__device__ __forceinline__ unsigned short f2bf(float f) {
  unsigned u = __builtin_bit_cast(unsigned, f);
  u += 0x7fffu + ((u >> 16) & 1u);   // RTNE
  return (unsigned short)(u >> 16);
}

__device__ __forceinline__ bf16x8 cvt8(float4 a, float4 b) {
  bf16x8 r;
  r[0] = (__bf16)a.x; r[1] = (__bf16)a.y; r[2] = (__bf16)a.z; r[3] = (__bf16)a.w;
  r[4] = (__bf16)b.x; r[5] = (__bf16)b.y; r[6] = (__bf16)b.z; r[7] = (__bf16)b.w;
  return r;
}

// stage a 16x128 C-layout tile (relu'd) into a 4KB LDS buffer, XOR-swizzled
// (HW-verified in rounds 1/3)
__device__ __forceinline__ void stage_h(char* bufj, const f32x4* accv, int grp, int row16) {
#pragma unroll
  for (int nt = 0; nt < 8; ++nt)
#pragma unroll
    for (int i = 0; i < 4; ++i) {
      const int r = grp * 4 + i;
      const int c = nt * 16 + row16;
      *(unsigned short*)(bufj + ((r * 256 + c * 2) ^ ((r & 7) << 4))) =
          f2bf(fmaxf(accv[nt][i], 0.f));
    }
}

// read an A-fragment (16 rows x 32 k) from a swizzled 4KB buffer (HW-verified)
__device__ __forceinline__ bf16x8 read_a(const char* bufj, int kt, int grp, int row16) {
  return *(const bf16x8*)(bufj + ((row16 * 256 + kt * 64 + grp * 16) ^ ((row16 & 7) << 4)));
}

// ---------- kernel 1: pack all weights to bf16 K32 B-frag order (verified layout)
// + convert node table to bf16 ----------
__global__ void pack_prep(const float* __restrict__ w0, const float* __restrict__ w1,
                          const float* __restrict__ w2, const float* __restrict__ nw0,
                          const float* __restrict__ nw1, const float* __restrict__ nw2,
                          const float* __restrict__ wn, const float* __restrict__ nodes,
                          unsigned short* __restrict__ dst, unsigned short* __restrict__ nbf) {
  int tid = blockIdx.x * blockDim.x + threadIdx.x;
  if (tid >= 163840 + N_NODES * DF) return;
  if (tid >= 163840) {                       // nodes -> bf16
    int p = tid - 163840;
    nbf[p] = f2bf(nodes[p]);
    return;
  }
  const float* src; int p;
  if (tid < 49152)       { src = w0;  p = tid; }
  else if (tid < 65536)  { src = w1;  p = tid - 49152; }
  else if (tid < 81920)  { src = w2;  p = tid - 65536; }
  else if (tid < 114688) { src = nw0; p = tid - 81920; }
  else if (tid < 131072) { src = nw1; p = tid - 114688; }
  else if (tid < 147456) { src = nw2; p = tid - 131072; }
  else                   { src = wn;  p = tid - 147456; }
  int i = p & 7, lane = (p >> 3) & 63, tile = p >> 9;
  int nt = tile & 7, kt = tile >> 3;
  int k = kt * 32 + ((lane >> 4) << 3) + i;
  int n = nt * 16 + (lane & 15);
  dst[tid] = f2bf(src[k * 128 + n]);
}

// ---------- kernel 2: fused message MLP + scatter-add ----------
// 256 thr = 4 waves, 64 edges/wave (4 subtiles of 16), 256 edges/block, grid 2500.
// Weights streamed from L2 amortized over 4 subtiles; edge rows (the only HBM
// stream) explicitly prefetched ahead of use; h-transposes via per-wave LDS.
__global__ void __launch_bounds__(256, 2) msg_kernel(
    const float* __restrict__ edges,
    const int* __restrict__ senders, const int* __restrict__ receivers,
    const float* __restrict__ b0, const float* __restrict__ b1, const float* __restrict__ b2,
    const unsigned short* __restrict__ pw, const unsigned short* __restrict__ nbf,
    float* __restrict__ agg) {
  __shared__ char hs[65536];
  const int tid = threadIdx.x;
  const int lane = tid & 63, wave = tid >> 6;
  const int row16 = lane & 15, grp = lane >> 4;
  char* hb = hs + wave * 16384;
  const int rbase = blockIdx.x * 256 + wave * 64;

  // edge indices + gather indices
  int sx[4], rx[4];
#pragma unroll
  for (int s = 0; s < 4; ++s) {
    sx[s] = senders[rbase + s * 16 + row16];
    rx[s] = receivers[rbase + s * 16 + row16];
  }

  // ---- prefetch edge rows for subtiles 0,1 (HBM stream, no indirection) ----
  float4 e01[2][4][2];
#pragma unroll
  for (int s = 0; s < 2; ++s)
#pragma unroll
    for (int k2 = 0; k2 < 4; ++k2) {
      const float* p = edges + (size_t)(rbase + s * 16 + row16) * DF + k2 * 32 + grp * 8;
      e01[s][k2][0] = *(const float4*)p;
      e01[s][k2][1] = *(const float4*)(p + 4);
    }

  f32x4 acc[4][8];
#pragma unroll
  for (int nt = 0; nt < 8; ++nt) {
    float bv = b0[nt * 16 + row16];
#pragma unroll
    for (int s = 0; s < 4; ++s) acc[s][nt] = (f32x4){bv, bv, bv, bv};
  }

  // ---- layer 0, kc=0: sender gathers (L2) ----
#pragma unroll
  for (int k2 = 0; k2 < 4; ++k2) {
    bf16x8 af[4];
#pragma unroll
    for (int s = 0; s < 4; ++s)
      af[s] = *(const bf16x8*)(nbf + (size_t)sx[s] * DF + k2 * 32 + grp * 8);
#pragma unroll
    for (int nt = 0; nt < 8; ++nt) {
      bf16x8 bw = *(const bf16x8*)(pw + ((size_t)(k2 * 8 + nt) * 64 + lane) * 8);
#pragma unroll
      for (int s = 0; s < 4; ++s)
        acc[s][nt] = __builtin_amdgcn_mfma_f32_16x16x32_bf16(af[s], bw, acc[s][nt], 0, 0, 0);
    }
  }

  // s0/s1 edge data has ~arrived: convert to bf16, freeing 8 float4 regs
  bf16x8 e01b[2][4];
#pragma unroll
  for (int s = 0; s < 2; ++s)
#pragma unroll
    for (int k2 = 0; k2 < 4; ++k2) e01b[s][k2] = cvt8(e01[s][k2][0], e01[s][k2][1]);

  // issue s2/s3 edge loads now; they hide under kc=1 compute + kc=2 s0/s1 compute
  float4 e23[2][4][2];
#pragma unroll
  for (int s = 0; s < 2; ++s)
#pragma unroll
    for (int k2 = 0; k2 < 4; ++k2) {
      const float* p = edges + (size_t)(rbase + (s + 2) * 16 + row16) * DF + k2 * 32 + grp * 8;
      e23[s][k2][0] = *(const float4*)p;
      e23[s][k2][1] = *(const float4*)(p + 4);
    }

  // ---- layer 0, kc=1: receiver gathers (L2) ----
#pragma unroll
  for (int k2 = 0; k2 < 4; ++k2) {
    bf16x8 af[4];
#pragma unroll
    for (int s = 0; s < 4; ++s)
      af[s] = *(const bf16x8*)(nbf + (size_t)rx[s] * DF + k2 * 32 + grp * 8);
#pragma unroll
    for (int nt = 0; nt < 8; ++nt) {
      bf16x8 bw = *(const bf16x8*)(pw + ((size_t)((4 + k2) * 8 + nt) * 64 + lane) * 8);
#pragma unroll
      for (int s = 0; s < 4; ++s)
        acc[s][nt] = __builtin_amdgcn_mfma_f32_16x16x32_bf16(af[s], bw, acc[s][nt], 0, 0, 0);
    }
  }

  // ---- layer 0, kc=2: edge features (prefetched) ----
#pragma unroll
  for (int k2 = 0; k2 < 4; ++k2) {
    bf16x8 af[4];
    af[0] = e01b[0][k2];
    af[1] = e01b[1][k2];
    af[2] = cvt8(e23[0][k2][0], e23[0][k2][1]);
    af[3] = cvt8(e23[1][k2][0], e23[1][k2][1]);
#pragma unroll
    for (int nt = 0; nt < 8; ++nt) {
      bf16x8 bw = *(const bf16x8*)(pw + ((size_t)((8 + k2) * 8 + nt) * 64 + lane) * 8);
#pragma unroll
      for (int s = 0; s < 4; ++s)
        acc[s][nt] = __builtin_amdgcn_mfma_f32_16x16x32_bf16(af[s], bw, acc[s][nt], 0, 0, 0);
    }
  }

  // ---- transpose h1 (all 4 subtiles) through per-wave LDS ----
#pragma unroll
  for (int s = 0; s < 4; ++s) stage_h(hb + s * 4096, acc[s], grp, row16);
  asm volatile("s_waitcnt lgkmcnt(0)" ::: "memory");
  __builtin_amdgcn_sched_barrier(0);

  // ---- layer 1 ----
  f32x4 acc2[4][8];
#pragma unroll
  for (int nt = 0; nt < 8; ++nt) {
    float bv = b1[nt * 16 + row16];
#pragma unroll
    for (int s = 0; s < 4; ++s) acc2[s][nt] = (f32x4){bv, bv, bv, bv};
  }
  const unsigned short* w1p = pw + 49152;
#pragma unroll
  for (int kt = 0; kt < 4; ++kt) {
    bf16x8 af[4];
#pragma unroll
    for (int s = 0; s < 4; ++s) af[s] = read_a(hb + s * 4096, kt, grp, row16);
#pragma unroll
    for (int nt = 0; nt < 8; ++nt) {
      bf16x8 bw = *(const bf16x8*)(w1p + ((size_t)(kt * 8 + nt) * 64 + lane) * 8);
#pragma unroll
      for (int s = 0; s < 4; ++s)
        acc2[s][nt] = __builtin_amdgcn_mfma_f32_16x16x32_bf16(af[s], bw, acc2[s][nt], 0, 0, 0);
    }
  }
  asm volatile("s_waitcnt lgkmcnt(0)" ::: "memory");  // reads done before overwrite
  __builtin_amdgcn_sched_barrier(0);

#pragma unroll
  for (int s = 0; s < 4; ++s) stage_h(hb + s * 4096, acc2[s], grp, row16);
  asm volatile("s_waitcnt lgkmcnt(0)" ::: "memory");
  __builtin_amdgcn_sched_barrier(0);

  // scatter indices (issued early so they're ready after layer 2)
  int rr[4][4];
#pragma unroll
  for (int s = 0; s < 4; ++s)
#pragma unroll
    for (int i = 0; i < 4; ++i) rr[s][i] = receivers[rbase + s * 16 + grp * 4 + i];

  // ---- layer 2 (no relu) ----
  f32x4 acc3[4][8];
#pragma unroll
  for (int nt = 0; nt < 8; ++nt) {
    float bv = b2[nt * 16 + row16];
#pragma unroll
    for (int s = 0; s < 4; ++s) acc3[s][nt] = (f32x4){bv, bv, bv, bv};
  }
  const unsigned short* w2p = pw + 65536;
#pragma unroll
  for (int kt = 0; kt < 4; ++kt) {
    bf16x8 af[4];
#pragma unroll
    for (int s = 0; s < 4; ++s) af[s] = read_a(hb + s * 4096, kt, grp, row16);
#pragma unroll
    for (int nt = 0; nt < 8; ++nt) {
      bf16x8 bw = *(const bf16x8*)(w2p + ((size_t)(kt * 8 + nt) * 64 + lane) * 8);
#pragma unroll
      for (int s = 0; s < 4; ++s)
        acc3[s][nt] = __builtin_amdgcn_mfma_f32_16x16x32_bf16(af[s], bw, acc3[s][nt], 0, 0, 0);
    }
  }

  // ---- scatter (verified indexing) ----
#pragma unroll
  for (int s = 0; s < 4; ++s)
#pragma unroll
    for (int nt = 0; nt < 8; ++nt)
#pragma unroll
      for (int i = 0; i < 4; ++i)
        unsafeAtomicAdd(agg + (size_t)rr[s][i] * DF + nt * 16 + row16, acc3[s][nt][i]);
}

// ---------- kernel 3: node MLP + residual + LayerNorm (verified, unchanged) ----------
__global__ void __launch_bounds__(256) node_kernel(
    const float* __restrict__ nodes, const float* __restrict__ agg,
    const float* __restrict__ nb0, const float* __restrict__ nb1, const float* __restrict__ nb2,
    const unsigned short* __restrict__ pnw0, const unsigned short* __restrict__ pnw1,
    const unsigned short* __restrict__ pnw2, const unsigned short* __restrict__ pwn,
    const float* __restrict__ ln_s, const float* __restrict__ ln_b,
    float* __restrict__ out) {
  __shared__ char hs[16384];
  const int tid = threadIdx.x, lane = tid & 63, wave = tid >> 6;
  const int row16 = lane & 15, grp = lane >> 4;
  char* hb = hs + wave * 4096;
  const int rb = blockIdx.x * 64 + wave * 16;
  const int rA = min(rb + row16, N_NODES - 1);

  f32x4 acc[8];
#pragma unroll
  for (int nt = 0; nt < 8; ++nt) {
    float b = nb0[nt * 16 + row16];
    acc[nt] = (f32x4){b, b, b, b};
  }
#pragma unroll
  for (int kt = 0; kt < 8; ++kt) {
    const float* p = (kt < 4) ? (nodes + (size_t)rA * DF + kt * 32)
                              : (agg + (size_t)rA * DF + (kt - 4) * 32);
    p += grp * 8;
    float4 f0 = *(const float4*)p, f1 = *(const float4*)(p + 4);
    bf16x8 af = cvt8(f0, f1);
#pragma unroll
    for (int nt = 0; nt < 8; ++nt) {
      bf16x8 bw = *(const bf16x8*)(pnw0 + ((size_t)(kt * 8 + nt) * 64 + lane) * 8);
      acc[nt] = __builtin_amdgcn_mfma_f32_16x16x32_bf16(af, bw, acc[nt], 0, 0, 0);
    }
  }
  stage_h(hb, acc, grp, row16);
  asm volatile("s_waitcnt lgkmcnt(0)" ::: "memory");
  __builtin_amdgcn_sched_barrier(0);

  f32x4 acc2[8];
#pragma unroll
  for (int nt = 0; nt < 8; ++nt) {
    float b = nb1[nt * 16 + row16];
    acc2[nt] = (f32x4){b, b, b, b};
  }
#pragma unroll
  for (int kt = 0; kt < 4; ++kt) {
    bf16x8 af = read_a(hb, kt, grp, row16);
#pragma unroll
    for (int nt = 0; nt < 8; ++nt) {
      bf16x8 bw = *(const bf16x8*)(pnw1 + ((size_t)(kt * 8 + nt) * 64 + lane) * 8);
      acc2[nt] = __builtin_amdgcn_mfma_f32_16x16x32_bf16(af, bw, acc2[nt], 0, 0, 0);
    }
  }
  asm volatile("s_waitcnt lgkmcnt(0)" ::: "memory");
  __builtin_amdgcn_sched_barrier(0);
  stage_h(hb, acc2, grp, row16);
  asm volatile("s_waitcnt lgkmcnt(0)" ::: "memory");
  __builtin_amdgcn_sched_barrier(0);

  f32x4 acc3[8];
#pragma unroll
  for (int nt = 0; nt < 8; ++nt) {
    float b = nb2[nt * 16 + row16];
    acc3[nt] = (f32x4){b, b, b, b};
  }
#pragma unroll
  for (int kt = 0; kt < 4; ++kt) {
    bf16x8 af = read_a(hb, kt, grp, row16);
#pragma unroll
    for (int nt = 0; nt < 8; ++nt) {
      bf16x8 bw = *(const bf16x8*)(pnw2 + ((size_t)(kt * 8 + nt) * 64 + lane) * 8);
      acc3[nt] = __builtin_amdgcn_mfma_f32_16x16x32_bf16(af, bw, acc3[nt], 0, 0, 0);
    }
  }
  f32x4 accR[8];
#pragma unroll
  for (int nt = 0; nt < 8; ++nt) accR[nt] = (f32x4){0.f, 0.f, 0.f, 0.f};
#pragma unroll
  for (int kt = 0; kt < 4; ++kt) {
    const float* p = nodes + (size_t)rA * DF + kt * 32 + grp * 8;
    float4 f0 = *(const float4*)p, f1 = *(const float4*)(p + 4);
    bf16x8 af = cvt8(f0, f1);
#pragma unroll
    for (int nt = 0; nt < 8; ++nt) {
      bf16x8 bw = *(const bf16x8*)(pwn + ((size_t)(kt * 8 + nt) * 64 + lane) * 8);
      accR[nt] = __builtin_amdgcn_mfma_f32_16x16x32_bf16(af, bw, accR[nt], 0, 0, 0);
    }
  }

  float y[8][4];
#pragma unroll
  for (int nt = 0; nt < 8; ++nt)
#pragma unroll
    for (int i = 0; i < 4; ++i) y[nt][i] = acc3[nt][i] + accR[nt][i];

  float mean[4], rstd[4];
#pragma unroll
  for (int i = 0; i < 4; ++i) {
    float s = 0.f;
#pragma unroll
    for (int nt = 0; nt < 8; ++nt) s += y[nt][i];
    s += __shfl_xor(s, 1); s += __shfl_xor(s, 2);
    s += __shfl_xor(s, 4); s += __shfl_xor(s, 8);
    mean[i] = s * (1.0f / 128.0f);
  }
#pragma unroll
  for (int i = 0; i < 4; ++i) {
    float v = 0.f;
#pragma unroll
    for (int nt = 0; nt < 8; ++nt) {
      float d = y[nt][i] - mean[i];
      v += d * d;
    }
    v += __shfl_xor(v, 1); v += __shfl_xor(v, 2);
    v += __shfl_xor(v, 4); v += __shfl_xor(v, 8);
    rstd[i] = rsqrtf(v * (1.0f / 128.0f) + 1e-6f);
  }
#pragma unroll
  for (int nt = 0; nt < 8; ++nt) {
    const float ls = ln_s[nt * 16 + row16];
    const float lb = ln_b[nt * 16 + row16];
#pragma unroll
    for (int i = 0; i < 4; ++i) {
      const int r = rb + grp * 4 + i;
      if (r < N_NODES)
        out[(size_t)r * DF + nt * 16 + row16] = (y[nt][i] - mean[i]) * rstd[i] * ls + lb;
    }
  }
}

// ---------- launch ----------
extern "C" void kernel_launch(void* const* d_in, const int* in_sizes, int n_in,
                              void* d_out, int out_size, void* d_ws, size_t ws_size,
                              hipStream_t stream) {
  const float* nodes     = (const float*)d_in[0];
  const float* edges     = (const float*)d_in[1];
  const int*   senders   = (const int*)d_in[2];
  const int*   receivers = (const int*)d_in[3];
  const float* msg_w0 = (const float*)d_in[4];
  const float* msg_b0 = (const float*)d_in[5];
  const float* msg_w1 = (const float*)d_in[6];
  const float* msg_b1 = (const float*)d_in[7];
  const float* msg_w2 = (const float*)d_in[8];
  const float* msg_b2 = (const float*)d_in[9];
  const float* node_w0 = (const float*)d_in[10];
  const float* node_b0 = (const float*)d_in[11];
  const float* node_w1 = (const float*)d_in[12];
  const float* node_b1 = (const float*)d_in[13];
  const float* node_w2 = (const float*)d_in[14];
  const float* node_b2 = (const float*)d_in[15];
  const float* w_node   = (const float*)d_in[16];
  const float* ln_scale = (const float*)d_in[17];
  const float* ln_bias  = (const float*)d_in[18];

  float* agg = (float*)d_ws;                                         // 5,120,000 B
  unsigned short* pw  = (unsigned short*)((char*)d_ws + 5120000);    // 327,680 B
  unsigned short* nbf = (unsigned short*)((char*)d_ws + 5447680);    // 2,560,000 B

  hipMemsetAsync(agg, 0, (size_t)N_NODES * DF * sizeof(float), stream);
  pack_prep<<<(163840 + N_NODES * DF) / 256, 256, 0, stream>>>(
      msg_w0, msg_w1, msg_w2, node_w0, node_w1, node_w2, w_node, nodes, pw, nbf);

  msg_kernel<<<N_EDGES / 256, 256, 0, stream>>>(
      edges, senders, receivers, msg_b0, msg_b1, msg_b2, pw, nbf, agg);

  node_kernel<<<157, 256, 0, stream>>>(nodes, agg, node_b0, node_b1, node_b2,
                                       pw + 81920, pw + 114688, pw + 131072, pw + 147456,
                                       ln_scale, ln_bias, (float*)d_out);
}